// Round 1
// baseline (139.977 us; speedup 1.0000x reference)
//
#include <hip/hip_runtime.h>

// QuantLinear: out[8,11008] = x[8,4096] @ W[11008,4096]^T
// packed[i] (INT32, one per byte!) holds 2 nibbles: low = weight 2i, high = weight 2i+1;
// weight = (q-8)*scale[idx/32]. 2048 int32 per row of 4096 k.
//
// R9: occupancy + cross-group pipeline attack on R8's 139 us (= 11% of HBM -> stall-bound).
//   - Split-K=8 (512-k strip): LDS 32->16 KB, per-thread load regs halved.
//   - 2 row-groups per WG, register-double-buffered:
//       x loads -> g0 weight loads -> ds_write x -> barrier (drains g0; consumed next)
//       -> issue g1 weight loads (in flight across g0 compute) -> compute g0 -> compute g1
//   - __launch_bounds__(256,4): cap 128 VGPR (est. ~110 live) => >=16 waves/CU.
//   Grid: 344 group-pairs x 8 k-strips = 2752 WGs x 256 thr. Wave: 4 rows/group;
//   lane owns 4 consecutive k: weights int2/row/tile (512 B/wave-instr), x ds_read_b128
//   at lane*16 B (conflict-free). Epilogue per group: 5-step shfl_xor tree + xor32;
//   lanes 0-31 atomicAdd (out memset to 0).

#define OUT_F 11008
#define IN_F  4096

__device__ __forceinline__ void group_compute(
    const float* xs, const int2 (&wq)[2][4], const float (&sc)[2][4],
    int lane, int rbase, float* __restrict__ out)
{
    float acc[32];                                // acc[r*8 + m]
#pragma unroll
    for (int i = 0; i < 32; ++i) acc[i] = 0.f;

#pragma unroll
    for (int t = 0; t < 2; ++t) {
        float w[4][4];
#pragma unroll
        for (int r = 0; r < 4; ++r) {
            const int   px = wq[t][r].x, py = wq[t][r].y;
            const float s  = sc[t][r];
            const float ns = -8.f * s;
            w[r][0] = fmaf((float)(px & 15), s, ns);   // k+0
            w[r][1] = fmaf((float)(px >> 4), s, ns);   // k+1 (byte < 256: no &15 needed)
            w[r][2] = fmaf((float)(py & 15), s, ns);   // k+2
            w[r][3] = fmaf((float)(py >> 4), s, ns);   // k+3
        }

        const int kl = t * 256 + lane * 4;             // local k in strip
#pragma unroll
        for (int m = 0; m < 8; ++m) {
            const float4 xa = *(const float4*)(xs + m * 512 + kl);  // ds_read_b128
#pragma unroll
            for (int r = 0; r < 4; ++r) {
                float a = acc[r * 8 + m];
                a = fmaf(w[r][0], xa.x, a);
                a = fmaf(w[r][1], xa.y, a);
                a = fmaf(w[r][2], xa.z, a);
                a = fmaf(w[r][3], xa.w, a);
                acc[r * 8 + m] = a;
            }
        }
    }

    // ---- merge tree over 32 values: lane l<32 ends with wave-total for index l ----
#pragma unroll
    for (int st = 0; st < 5; ++st) {
        const int bit = (lane >> st) & 1;
        const int n = 16 >> st;
#pragma unroll
        for (int jj = 0; jj < n; ++jj) {
            const float u = bit ? acc[2 * jj + 1] : acc[2 * jj];
            const float v = bit ? acc[2 * jj]     : acc[2 * jj + 1];
            acc[jj] = u + __shfl_xor(v, 1 << st, 64);
        }
    }
    acc[0] += __shfl_xor(acc[0], 32, 64);

    if (lane < 32) {
        const int r = lane >> 3;                       // index l = r*8 + m
        const int m = lane & 7;
        atomicAdd(out + m * OUT_F + rbase + r, acc[0]);
    }
}

__global__ __launch_bounds__(256, 4) void qlin_kernel(
    const float* __restrict__ x,
    const int*   __restrict__ packed,
    const float* __restrict__ scales,
    float*       __restrict__ out)
{
    const int tid  = threadIdx.x;
    const int lane = tid & 63;
    const int wave = tid >> 6;
    const int b    = blockIdx.x;
    const int e    = b & 7;                  // k-strip 0..7 (512 k each)
    const int j    = b >> 3;                 // row-group pair 0..343
    const int ke   = e << 9;                 // global k base of strip

    __shared__ float xs[8 * 512];            // 16 KB

    // ---- 1) x loads FIRST: oldest entries in the vmcnt queue ----
    float4 xv[4];
    {
        const float* xg = x + ke;
#pragma unroll
        for (int i = 0; i < 4; ++i) {
            const int f  = tid + (i << 8);        // float4 id 0..1023
            const int m  = f >> 7;
            const int kv = (f & 127) << 2;
            xv[i] = *(const float4*)(xg + m * IN_F + kv);
        }
    }

    // ---- 2) group-0 weight + scale loads (int32 units: lane*2 dwords = 4 k) ----
    const int g0   = j * 2;
    const int row0 = g0 * 16 + wave * 4;          // group-0 wave rows
    int2  wqA[2][4]; float scA[2][4];
    {
        const int pb = row0 * 2048 + (ke >> 1) + lane * 2;
        const int sb = row0 * 128  + (ke >> 5) + (lane >> 3);
#pragma unroll
        for (int t = 0; t < 2; ++t)
#pragma unroll
            for (int r = 0; r < 4; ++r) {
                wqA[t][r] = *(const int2*)(packed + pb + r * 2048 + t * 128);
                scA[t][r] = scales[sb + r * 128 + t * 8];
            }
    }

    // ---- 3) stage x (waits only the 4 oldest loads), barrier drains g0 loads ----
#pragma unroll
    for (int i = 0; i < 4; ++i) {
        const int f  = tid + (i << 8);
        const int m  = f >> 7;
        const int kv = (f & 127) << 2;
        *(float4*)(xs + m * 512 + kv) = xv[i];
    }
    __syncthreads();

    // ---- 4) group-1 loads: issued now, in flight across ALL of group-0 compute ----
    const int row1 = row0 + 16;
    int2  wqB[2][4]; float scB[2][4];
    {
        const int pb = row1 * 2048 + (ke >> 1) + lane * 2;
        const int sb = row1 * 128  + (ke >> 5) + (lane >> 3);
#pragma unroll
        for (int t = 0; t < 2; ++t)
#pragma unroll
            for (int r = 0; r < 4; ++r) {
                wqB[t][r] = *(const int2*)(packed + pb + r * 2048 + t * 128);
                scB[t][r] = scales[sb + r * 128 + t * 8];
            }
    }

    // ---- 5) compute: g0 (regs ready at barrier), then g1 (latency hidden) ----
    group_compute(xs, wqA, scA, lane, row0, out);
    group_compute(xs, wqB, scB, lane, row1, out);
}

extern "C" void kernel_launch(void* const* d_in, const int* in_sizes, int n_in,
                              void* d_out, int out_size, void* d_ws, size_t ws_size,
                              hipStream_t stream) {
    const float* x      = (const float*)d_in[0];
    const int*   packed = (const int*)  d_in[1];
    const float* scales = (const float*)d_in[2];
    float*       out    = (float*)d_out;

    // split-K atomics accumulate into out -> zero it first (async, graph-capturable)
    hipMemsetAsync(out, 0, (size_t)out_size * sizeof(float), stream);

    dim3 grid((OUT_F / 32) * 8), block(256);      // 2752 WGs x 4 waves
    hipLaunchKernelGGL(qlin_kernel, grid, block, 0, stream,
                       x, packed, scales, out);
}